// Round 8
// baseline (232.324 us; speedup 1.0000x reference)
//
#include <hip/hip_runtime.h>
#include <hip/hip_bf16.h>

// LPLayer: e = x@W^T + b; lp = relu(tanh(e@e^T)); nf = lp@e / N
// B=8, N=2048, C_IN=128, D(C_OUT)=64. All I/O **fp32** (reference dtypes).
// d_out (float) = [nf (8*2048*64)] ++ [lp (8*2048*2048)]

#define B_    8
#define N_    2048
#define D_    64
#define CIN_  128

typedef __bf16 bf16x8 __attribute__((ext_vector_type(8)));
typedef float f32x4  __attribute__((ext_vector_type(4)));

union FragU { uint4 u; bf16x8 f; };

static __device__ __forceinline__ bf16x8 ld_frag(const __hip_bfloat16* p) {
    FragU fu; fu.u = *reinterpret_cast<const uint4*>(p); return fu.f;
}

static __device__ __forceinline__ void st_frag(__hip_bfloat16* p, bf16x8 f) {
    FragU fu; fu.f = f; *reinterpret_cast<uint4*>(p) = fu.u;
}

// Split 8 consecutive fp32 into hi/lo bf16x8 (hi = RTN(v), lo = RTN(v - hi)).
static __device__ __forceinline__ void split8(const float* p, bf16x8& hi, bf16x8& lo) {
    const float4 a = *reinterpret_cast<const float4*>(p);
    const float4 b = *reinterpret_cast<const float4*>(p + 4);
    const float v[8] = {a.x, a.y, a.z, a.w, b.x, b.y, b.z, b.w};
#pragma unroll
    for (int i = 0; i < 8; i++) {
        const __bf16 h = (__bf16)v[i];
        hi[i] = h;
        lo[i] = (__bf16)(v[i] - (float)h);
    }
}

// Convert 8 consecutive fp32 (LDS) to bf16x8.
static __device__ __forceinline__ bf16x8 cvt8(const float* p) {
    const float4 a = *reinterpret_cast<const float4*>(p);
    const float4 b = *reinterpret_cast<const float4*>(p + 4);
    bf16x8 r;
    r[0] = (__bf16)a.x; r[1] = (__bf16)a.y; r[2] = (__bf16)a.z; r[3] = (__bf16)a.w;
    r[4] = (__bf16)b.x; r[5] = (__bf16)b.y; r[6] = (__bf16)b.z; r[7] = (__bf16)b.w;
    return r;
}

// Barrier that waits ONLY on LDS ops (lgkmcnt), never vmcnt: in-flight
// prefetch loads and NT store drains survive across it. sched_barrier(0)
// stops post-barrier LDS reads hoisting above (rule #18).
static __device__ __forceinline__ void lds_barrier() {
    asm volatile("s_waitcnt lgkmcnt(0)" ::: "memory");
    __builtin_amdgcn_s_barrier();
    __builtin_amdgcn_sched_barrier(0);
}

// ---------------------------------------------------------------------------
// Kernel 1: e = x @ W^T + b (fp32 in), emit e_hi/e_lo (bf16 split) and
// e_hiT ([B][64][N] transposed bf16 for K2's PV B-operand).
// Split-MFMA: e = xh*wh + xh*wl + xl*wh  (error ~4e-6).
// Grid: 256 blocks x 256 thr (4 waves); wave = 16 rows x 64 chans.
// W hi/lo split staged ONCE per block into LDS; e_hiT stores packed 8 B.
// ---------------------------------------------------------------------------
#define LDW  136  // W LDS row stride, bf16 elems (128 + 8 pad -> 2-way banks)

__global__ __launch_bounds__(256) void ex_kernel(
    const float* __restrict__ x,
    const float* __restrict__ W,
    const float* __restrict__ bias,
    __hip_bfloat16* __restrict__ e_hi,
    __hip_bfloat16* __restrict__ e_lo,
    __hip_bfloat16* __restrict__ e_hiT)
{
    __shared__ __align__(16) __hip_bfloat16 sW[2 * 64 * LDW];  // 34.8 KB
    __hip_bfloat16* sWhi = sW;
    __hip_bfloat16* sWlo = sW + 64 * LDW;

    const int tid  = threadIdx.x;

    // ---- stage W split into LDS: 64 rows x 128, 1024 chunks of 8 ----
#pragma unroll
    for (int p = 0; p < 4; p++) {
        const int q = tid + p * 256;
        const int r = q >> 4, c = (q & 15) * 8;
        bf16x8 hi, lo;
        split8(W + (size_t)r * CIN_ + c, hi, lo);
        st_frag(sWhi + r * LDW + c, hi);
        st_frag(sWlo + r * LDW + c, lo);
    }
    __syncthreads();

    const int w    = tid >> 6;
    const int lane = tid & 63;
    const int quad = lane >> 4;
    const int l16  = lane & 15;
    const int m0   = blockIdx.x * 64 + w * 16;   // 16 rows per wave

    // A-frags: A[m=lane&15][k=quad*8+j], 4 ksteps over K=128
    const float* xrow = x + (size_t)(m0 + l16) * CIN_;
    bf16x8 ah[4], al[4];
#pragma unroll
    for (int ks = 0; ks < 4; ks++)
        split8(xrow + ks * 32 + quad * 8, ah[ks], al[ks]);

    f32x4 acc[4];
#pragma unroll
    for (int nt = 0; nt < 4; nt++) acc[nt] = f32x4{0.f, 0.f, 0.f, 0.f};

#pragma unroll
    for (int ks = 0; ks < 4; ks++) {
#pragma unroll
        for (int nt = 0; nt < 4; nt++) {
            bf16x8 wh = ld_frag(sWhi + (nt * 16 + l16) * LDW + ks * 32 + quad * 8);
            bf16x8 wl = ld_frag(sWlo + (nt * 16 + l16) * LDW + ks * 32 + quad * 8);
            acc[nt] = __builtin_amdgcn_mfma_f32_16x16x32_bf16(ah[ks], wh, acc[nt], 0, 0, 0);
            acc[nt] = __builtin_amdgcn_mfma_f32_16x16x32_bf16(ah[ks], wl, acc[nt], 0, 0, 0);
            acc[nt] = __builtin_amdgcn_mfma_f32_16x16x32_bf16(al[ks], wh, acc[nt], 0, 0, 0);
        }
    }

    // Epilogue: bias, hi/lo split, stores. C/D: col=lane&15 (chan), row=quad*4+reg.
#pragma unroll
    for (int nt = 0; nt < 4; nt++) {
        const int chan = nt * 16 + l16;
        const float bv = bias[chan];
        union { __hip_bfloat16 h[4]; uint2 u2; } hv;
#pragma unroll
        for (int i = 0; i < 4; i++) {
            const int gr = m0 + quad * 4 + i;          // global row in [0, B*N)
            const float e = acc[nt][i] + bv;
            const __hip_bfloat16 hi = __float2bfloat16(e);
            const __hip_bfloat16 lo = __float2bfloat16(e - __bfloat162float(hi));
            e_hi[(size_t)gr * D_ + chan] = hi;
            e_lo[(size_t)gr * D_ + chan] = lo;
            hv.h[i] = hi;
        }
        // 4 consecutive ir rows (quad*4..+3, same bt always) -> one 8 B store
        const int gr0 = m0 + quad * 4;
        const int bt = gr0 >> 11, ir = gr0 & (N_ - 1);
        *reinterpret_cast<uint2*>(e_hiT + ((size_t)bt * D_ + chan) * N_ + ir) = hv.u2;
    }
}

// ---------------------------------------------------------------------------
// Kernel 2: fused Gram + tanh/relu + lp store + PV accumulate + nf store.
// v9 combines the three individually-confirmed mechanisms from v1-v8:
//   (1) 2 KB-contiguous lp flush (v8: scattered 64 B = 134 us, 2 KB rows
//       = ~75 us — DRAM write pattern is a real lever);
//   (2) NO per-jt barriers (v2->v3 and v8's cost structure: every in-loop
//       __syncthreads vmcnt(0) drain serializes the phase convoy);
//   (3) free-running waves with direct-L2 B-frag reads + one-jt-ahead
//       register prefetch (v4/v6's read side, exonerated).
// Structure: Gram (A=Ei regs, B=Ej prefetch regs) -> tanh/relu -> C-layout
// write into a [32][516] fp32 LDS accumulator slot (jt&3) -> SELF-read
// (wave's own 16x32 block) cvt8 -> PV A-frag -> PV MFMA (B = e_hiT direct,
// prefetched). Every 4 jt: flush 32 rows x 2 KB contiguous NT bursts,
// bracketed by the ONLY barriers (lgkmcnt-only, 8 total vs v8's 36 full
// drains). LDS 66,048 B -> 2 blocks/CU, 16 waves/CU free-running.
// Gram split: S = Eih*Ejh + Eih*Ejl + Eil*Ejh (identical term set/order ->
// absmax unchanged). PV self-containment verified in v8 (passed).
// Grid: (8 batches, 64 i-tiles) x 512 thr.
// Wave w: row-group g=w>>2 (16 i-rows), j/k-quarter h=w&3 (32 of 128).
// ---------------------------------------------------------------------------
#define LDG  516  // lp accumulator row stride, fp32 (512 + 4: 16B-mult, 2-way banks)

__global__ __launch_bounds__(512, 4) void fused_kernel(
    const __hip_bfloat16* __restrict__ e_hi,
    const __hip_bfloat16* __restrict__ e_lo,
    const __hip_bfloat16* __restrict__ e_hiT,
    float* __restrict__ out)
{
    // 32*516*4 = 66,048 B; epilogue overlays sO [8][16][68] fp32 (34,816 B).
    __shared__ __align__(16) float smem[32 * LDG];
    float* sLpF = smem;

    const int b   = blockIdx.x;          // batch (id%8: XCD-aligned)
    const int i0  = blockIdx.y * 32;
    const int tid = threadIdx.x;
    const int w = tid >> 6, lane = tid & 63, quad = lane >> 4, l16 = lane & 15;
    const int g = w >> 2, h = w & 3;
    const int m0 = i0 + g * 16;
    const int koff = h * 32 + quad * 8;  // wave's j/k quarter offset

    // Persistent Ei A-frags (hi & lo), K=64 -> 2 ksteps
    const __hip_bfloat16* eih = e_hi + (size_t)(b * N_ + m0 + l16) * D_;
    const __hip_bfloat16* eil = e_lo + (size_t)(b * N_ + m0 + l16) * D_;
    bf16x8 ahi[2], alo[2];
#pragma unroll
    for (int ks = 0; ks < 2; ks++) {
        ahi[ks] = ld_frag(eih + ks * 32 + quad * 8);
        alo[ks] = ld_frag(eil + ks * 32 + quad * 8);
    }

    // Ej B-frag prefetch regs [tile t][ks] (hi & lo), jt=0 preload.
    const __hip_bfloat16* bjh0 = e_hi + (size_t)(b * N_ + h * 32 + l16) * D_ + quad * 8;
    const __hip_bfloat16* bjl0 = e_lo + (size_t)(b * N_ + h * 32 + l16) * D_ + quad * 8;
    bf16x8 pbh[2][2], pbl[2][2];
#pragma unroll
    for (int t = 0; t < 2; t++)
#pragma unroll
        for (int ks = 0; ks < 2; ks++) {
            pbh[t][ks] = ld_frag(bjh0 + (size_t)(t * 16) * D_ + ks * 32);
            pbl[t][ks] = ld_frag(bjl0 + (size_t)(t * 16) * D_ + ks * 32);
        }

    // PV B-frag prefetch regs (e_hiT rows = channels, 16 B contiguous), jt=0.
    const __hip_bfloat16* ehT = e_hiT + ((size_t)(b * D_ + l16)) * N_ + koff;
    bf16x8 bb[4];
#pragma unroll
    for (int nt = 0; nt < 4; nt++)
        bb[nt] = ld_frag(ehT + (size_t)(nt * 16) * N_);

    f32x4 o[4];
#pragma unroll
    for (int nt = 0; nt < 4; nt++) o[nt] = f32x4{0.f, 0.f, 0.f, 0.f};

    float* lp_out = out + (size_t)B_ * N_ * D_;

    for (int jt = 0; jt < 16; jt++) {
        const int cb = (jt & 3) * 128;   // col base within accumulator

        // ---- Gram: S[16i x 32j] from registers (A=Ei, B=Ej prefetched) ----
        f32x4 s[2];
#pragma unroll
        for (int t = 0; t < 2; t++) {
            s[t] = f32x4{0.f, 0.f, 0.f, 0.f};
#pragma unroll
            for (int ks = 0; ks < 2; ks++) {
                s[t] = __builtin_amdgcn_mfma_f32_16x16x32_bf16(ahi[ks], pbh[t][ks], s[t], 0, 0, 0);
                s[t] = __builtin_amdgcn_mfma_f32_16x16x32_bf16(ahi[ks], pbl[t][ks], s[t], 0, 0, 0);
                s[t] = __builtin_amdgcn_mfma_f32_16x16x32_bf16(alo[ks], pbh[t][ks], s[t], 0, 0, 0);
            }
        }

        // ---- prefetch NEXT jt's Ej frags (in flight under trans+PV) ----
        {
            const size_t jn = (size_t)(((jt + 1) & 15) * 128) * D_;
#pragma unroll
            for (int t = 0; t < 2; t++)
#pragma unroll
                for (int ks = 0; ks < 2; ks++) {
                    pbh[t][ks] = ld_frag(bjh0 + jn + (size_t)(t * 16) * D_ + ks * 32);
                    pbl[t][ks] = ld_frag(bjl0 + jn + (size_t)(t * 16) * D_ + ks * 32);
                }
        }

        // ---- tanh/relu -> accumulator slot (C-layout: row=i, col=j) ----
#pragma unroll
        for (int t = 0; t < 2; t++) {
            const int n0 = h * 32 + t * 16;
#pragma unroll
            for (int i = 0; i < 4; i++) {
                // relu(tanh(x)) = tanh(max(x,0)) — clamp BEFORE exp2: no
                // overflow path, and fmaxf(NaN,0)=0 absorbs upstream garbage.
                const float tc = fmaxf(s[t][i], 0.0f);
                const float z = __builtin_amdgcn_exp2f(tc * -2.8853900817779268f);
                const float v = (1.0f - z) * __builtin_amdgcn_rcpf(1.0f + z);
                sLpF[(g * 16 + quad * 4 + i) * LDG + cb + n0 + l16] = v;
            }
        }

        // ---- PV: self-read own 16x32 block (same-wave RAW, no barrier) ----
        {
            bf16x8 a = cvt8(sLpF + (g * 16 + l16) * LDG + cb + koff);
#pragma unroll
            for (int nt = 0; nt < 4; nt++)
                o[nt] = __builtin_amdgcn_mfma_f32_16x16x32_bf16(a, bb[nt], o[nt], 0, 0, 0);
        }

        // ---- prefetch NEXT jt's PV B-frags ----
        {
            const int j0n = ((jt + 1) & 15) * 128;
#pragma unroll
            for (int nt = 0; nt < 4; nt++)
                bb[nt] = ld_frag(ehT + (size_t)(nt * 16) * N_ + j0n);
        }

        // ---- flush every 4 jt: 32 rows x 2 KB contiguous NT bursts ----
        if ((jt & 3) == 3) {
            lds_barrier();   // all waves' slot writes visible (lgkmcnt-only)
            const int jc0 = (jt & ~3) * 128;   // global col of slot-0 col 0
#pragma unroll
            for (int p = 0; p < 8; p++) {
                const int q = p * 512 + tid;        // 0..4095 16B-units (64 KB)
                const int r = q >> 7;               // row 0..31
                const int c4 = (q & 127) * 4;       // col 0..508 (floats)
                __builtin_nontemporal_store(
                    *(const f32x4*)(sLpF + r * LDG + c4),
                    (f32x4*)(lp_out + ((size_t)(b * N_ + i0 + r)) * N_ + jc0 + c4));
            }
            lds_barrier();   // flush reads done before next superstep's writes
        }
    }

    // ---- epilogue: sum 4 j-quarter partials, /N, store node_feats (fp32) ----
    __syncthreads();   // full drain fine here (once, end of kernel)
    float* sO = smem;  // overlay (34.8 KB within 66 KB region)
#pragma unroll
    for (int nt = 0; nt < 4; nt++) {
#pragma unroll
        for (int i = 0; i < 4; i++) {
            const int row = quad * 4 + i;            // local row in group
            const int chan = nt * 16 + l16;
            sO[w * 1088 + row * 68 + chan] = o[nt][i];   // stride 68: 2-way banks
        }
    }
    __syncthreads();
    {
        const int row = tid >> 4;                    // 0..31
        const int c4  = (tid & 15) * 4;
        const int gg = row >> 4, rr = row & 15;
        const float* base = sO + (gg * 4) * 1088 + rr * 68 + c4;
        const float4 v0 = *(const float4*)(base);
        const float4 v1 = *(const float4*)(base + 1088);
        const float4 v2 = *(const float4*)(base + 2176);
        const float4 v3 = *(const float4*)(base + 3264);
        f32x4 r;
        r[0] = (v0.x + v1.x + v2.x + v3.x) * (1.0f / 2048.0f);
        r[1] = (v0.y + v1.y + v2.y + v3.y) * (1.0f / 2048.0f);
        r[2] = (v0.z + v1.z + v2.z + v3.z) * (1.0f / 2048.0f);
        r[3] = (v0.w + v1.w + v2.w + v3.w) * (1.0f / 2048.0f);
        *reinterpret_cast<f32x4*>(out + ((size_t)(b * N_ + i0 + row)) * D_ + c4) = r;
    }
}

// ---------------------------------------------------------------------------
extern "C" void kernel_launch(void* const* d_in, const int* in_sizes, int n_in,
                              void* d_out, int out_size, void* d_ws, size_t ws_size,
                              hipStream_t stream) {
    const float* x    = (const float*)d_in[0];
    const float* W    = (const float*)d_in[1];
    const float* bias = (const float*)d_in[2];
    float* out = (float*)d_out;

    __hip_bfloat16* e_hi  = (__hip_bfloat16*)d_ws;            // [B*N][64]
    __hip_bfloat16* e_lo  = e_hi + (size_t)B_ * N_ * D_;      // [B*N][64]
    __hip_bfloat16* e_hiT = e_lo + (size_t)B_ * N_ * D_;      // [B][64][N]

    ex_kernel<<<dim3(256), dim3(256), 0, stream>>>(x, W, bias, e_hi, e_lo, e_hiT);
    fused_kernel<<<dim3(8, 64), dim3(512), 0, stream>>>(e_hi, e_lo, e_hiT, out);
}

// Round 9
// 171.214 us; speedup vs baseline: 1.3569x; 1.3569x over previous
//
#include <hip/hip_runtime.h>
#include <hip/hip_bf16.h>

// LPLayer: e = x@W^T + b; lp = relu(tanh(e@e^T)); nf = lp@e / N
// B=8, N=2048, C_IN=128, D(C_OUT)=64. All I/O **fp32** (reference dtypes).
// d_out (float) = [nf (8*2048*64)] ++ [lp (8*2048*2048)]

#define B_    8
#define N_    2048
#define D_    64
#define CIN_  128

typedef __bf16 bf16x8 __attribute__((ext_vector_type(8)));
typedef float f32x4  __attribute__((ext_vector_type(4)));

union FragU { uint4 u; bf16x8 f; };

static __device__ __forceinline__ bf16x8 ld_frag(const __hip_bfloat16* p) {
    FragU fu; fu.u = *reinterpret_cast<const uint4*>(p); return fu.f;
}

static __device__ __forceinline__ void st_frag(__hip_bfloat16* p, bf16x8 f) {
    FragU fu; fu.f = f; *reinterpret_cast<uint4*>(p) = fu.u;
}

// Split 8 consecutive fp32 into hi/lo bf16x8 (hi = RTN(v), lo = RTN(v - hi)).
static __device__ __forceinline__ void split8(const float* p, bf16x8& hi, bf16x8& lo) {
    const float4 a = *reinterpret_cast<const float4*>(p);
    const float4 b = *reinterpret_cast<const float4*>(p + 4);
    const float v[8] = {a.x, a.y, a.z, a.w, b.x, b.y, b.z, b.w};
#pragma unroll
    for (int i = 0; i < 8; i++) {
        const __bf16 h = (__bf16)v[i];
        hi[i] = h;
        lo[i] = (__bf16)(v[i] - (float)h);
    }
}

// Convert 8 consecutive fp32 (LDS) to bf16x8.
static __device__ __forceinline__ bf16x8 cvt8(const float* p) {
    const float4 a = *reinterpret_cast<const float4*>(p);
    const float4 b = *reinterpret_cast<const float4*>(p + 4);
    bf16x8 r;
    r[0] = (__bf16)a.x; r[1] = (__bf16)a.y; r[2] = (__bf16)a.z; r[3] = (__bf16)a.w;
    r[4] = (__bf16)b.x; r[5] = (__bf16)b.y; r[6] = (__bf16)b.z; r[7] = (__bf16)b.w;
    return r;
}

// Barrier that waits ONLY on LDS ops (lgkmcnt), never vmcnt: in-flight
// prefetch loads and NT store drains survive across it. sched_barrier(0)
// stops post-barrier LDS reads hoisting above (rule #18).
static __device__ __forceinline__ void lds_barrier() {
    asm volatile("s_waitcnt lgkmcnt(0)" ::: "memory");
    __builtin_amdgcn_s_barrier();
    __builtin_amdgcn_sched_barrier(0);
}

// ---------------------------------------------------------------------------
// Kernel 1: e = x @ W^T + b (fp32 in), emit e_hi/e_lo (bf16 split) and
// e_hiT ([B][64][N] transposed bf16 for K2's PV B-operand).
// Split-MFMA: e = xh*wh + xh*wl + xl*wh  (error ~4e-6).
// Grid: 256 blocks x 256 thr (4 waves); wave = 16 rows x 64 chans.
// W hi/lo split staged ONCE per block into LDS; e_hiT stores packed 8 B.
// ---------------------------------------------------------------------------
#define LDW  136  // W LDS row stride, bf16 elems (128 + 8 pad -> 2-way banks)

__global__ __launch_bounds__(256) void ex_kernel(
    const float* __restrict__ x,
    const float* __restrict__ W,
    const float* __restrict__ bias,
    __hip_bfloat16* __restrict__ e_hi,
    __hip_bfloat16* __restrict__ e_lo,
    __hip_bfloat16* __restrict__ e_hiT)
{
    __shared__ __align__(16) __hip_bfloat16 sW[2 * 64 * LDW];  // 34.8 KB
    __hip_bfloat16* sWhi = sW;
    __hip_bfloat16* sWlo = sW + 64 * LDW;

    const int tid  = threadIdx.x;

    // ---- stage W split into LDS: 64 rows x 128, 1024 chunks of 8 ----
#pragma unroll
    for (int p = 0; p < 4; p++) {
        const int q = tid + p * 256;
        const int r = q >> 4, c = (q & 15) * 8;
        bf16x8 hi, lo;
        split8(W + (size_t)r * CIN_ + c, hi, lo);
        st_frag(sWhi + r * LDW + c, hi);
        st_frag(sWlo + r * LDW + c, lo);
    }
    __syncthreads();

    const int w    = tid >> 6;
    const int lane = tid & 63;
    const int quad = lane >> 4;
    const int l16  = lane & 15;
    const int m0   = blockIdx.x * 64 + w * 16;   // 16 rows per wave

    // A-frags: A[m=lane&15][k=quad*8+j], 4 ksteps over K=128
    const float* xrow = x + (size_t)(m0 + l16) * CIN_;
    bf16x8 ah[4], al[4];
#pragma unroll
    for (int ks = 0; ks < 4; ks++)
        split8(xrow + ks * 32 + quad * 8, ah[ks], al[ks]);

    f32x4 acc[4];
#pragma unroll
    for (int nt = 0; nt < 4; nt++) acc[nt] = f32x4{0.f, 0.f, 0.f, 0.f};

#pragma unroll
    for (int ks = 0; ks < 4; ks++) {
#pragma unroll
        for (int nt = 0; nt < 4; nt++) {
            bf16x8 wh = ld_frag(sWhi + (nt * 16 + l16) * LDW + ks * 32 + quad * 8);
            bf16x8 wl = ld_frag(sWlo + (nt * 16 + l16) * LDW + ks * 32 + quad * 8);
            acc[nt] = __builtin_amdgcn_mfma_f32_16x16x32_bf16(ah[ks], wh, acc[nt], 0, 0, 0);
            acc[nt] = __builtin_amdgcn_mfma_f32_16x16x32_bf16(ah[ks], wl, acc[nt], 0, 0, 0);
            acc[nt] = __builtin_amdgcn_mfma_f32_16x16x32_bf16(al[ks], wh, acc[nt], 0, 0, 0);
        }
    }

    // Epilogue: bias, hi/lo split, stores. C/D: col=lane&15 (chan), row=quad*4+reg.
#pragma unroll
    for (int nt = 0; nt < 4; nt++) {
        const int chan = nt * 16 + l16;
        const float bv = bias[chan];
        union { __hip_bfloat16 h[4]; uint2 u2; } hv;
#pragma unroll
        for (int i = 0; i < 4; i++) {
            const int gr = m0 + quad * 4 + i;          // global row in [0, B*N)
            const float e = acc[nt][i] + bv;
            const __hip_bfloat16 hi = __float2bfloat16(e);
            const __hip_bfloat16 lo = __float2bfloat16(e - __bfloat162float(hi));
            e_hi[(size_t)gr * D_ + chan] = hi;
            e_lo[(size_t)gr * D_ + chan] = lo;
            hv.h[i] = hi;
        }
        // 4 consecutive ir rows (quad*4..+3, same bt always) -> one 8 B store
        const int gr0 = m0 + quad * 4;
        const int bt = gr0 >> 11, ir = gr0 & (N_ - 1);
        *reinterpret_cast<uint2*>(e_hiT + ((size_t)bt * D_ + chan) * N_ + ir) = hv.u2;
    }
}

// ---------------------------------------------------------------------------
// Kernel 2: fused Gram + tanh/relu + fp32 lp store + PV accumulate + nf store.
// v10 = v2 (corrected-bookkeeping best: fused ~55 us; LDS-staged panels +
// ds_read frags beat all direct-L2-gather variants by ~2x — gathers at 128 B
// row stride fragment into ~16 transactions/instr on the TA/TCP pipe) with
// v2's two EXPOSED latencies removed:
//   (T14) panel staging is reg-staged issue-early/write-late: global loads
//         for jt+1 issue right after Bb and land in regs during jt's
//         Gram/trans/PV; consumed by ds_write a full phase later (counted
//         vmcnt, never 0). v2 issued+drained them inside one barrier gap.
//   (T4)  both per-jt barriers are lgkm-only: NT lp stores and in-flight
//         staged loads are NEVER vmcnt-drained in-loop (v2's __syncthreads
//         emitted vmcnt(0) twice per jt).
// Phase order per jt:  Ba -> [store lp(jt-1) from sLpF || ds_write panel jt]
//   -> Bb -> issue loads(jt+1) -> Gram(jt) -> trans(jt)->sLpF -> PV(jt).
// Race check: Ba fences {Gram/PV panel reads, trans sLpF writes} of jt-1
// before {panel writes, sLpF store-reads}; Bb fences those before
// {Gram reads, trans writes} of jt. PV self-reads its own 16x32 sLpF block
// (same-wave RAW, verified v8/v9). Store phase for jt=15 after the loop.
// LDS 71,168 B -> 2 blocks/CU (16 waves, the overlap v8 lost).
// Gram split: S = Ahi*Bhi + Ahi*Blo + Alo*Bhi (identical math to v2).
// Grid: (8 batches, 64 i-tiles) x 512 thr.
// ---------------------------------------------------------------------------
#define LDE  72   // E tile LDS row stride, bf16 (64 + 8 pad)
#define LDT  136  // EhiT LDS row stride, bf16 (128 + 8 pad)
#define LDF  132  // lp tile LDS row stride, fp32 (128 + 4 pad, 16B-mult)

__global__ __launch_bounds__(512, 4) void fused_kernel(
    const __hip_bfloat16* __restrict__ e_hi,
    const __hip_bfloat16* __restrict__ e_lo,
    const __hip_bfloat16* __restrict__ e_hiT,
    float* __restrict__ out)
{
    // 16896 (sLpF) + 18432*2 (sEhi/sElo) + 17408 (sEhiT) = 71,168 B
    __shared__ __align__(16) unsigned char smem[32 * LDF * 4 + 128 * LDE * 2 * 2 + 64 * LDT * 2];
    float*          sLpF  = (float*)smem;                           // [32][132] fp32
    __hip_bfloat16* sEhi  = (__hip_bfloat16*)(smem + 32 * LDF * 4); // [128][72]
    __hip_bfloat16* sElo  = sEhi + 128 * LDE;                       // [128][72]
    __hip_bfloat16* sEhiT = sElo + 128 * LDE;                       // [64][136]

    const int b   = blockIdx.x;          // batch (id%8: XCD-aligned)
    const int i0  = blockIdx.y * 32;
    const int tid = threadIdx.x;
    const int w = tid >> 6, lane = tid & 63, quad = lane >> 4, l16 = lane & 15;
    const int g = w >> 2, h = w & 3;
    const int m0 = i0 + g * 16;
    const int koff = h * 32 + quad * 8;  // wave's j/k quarter offset

    // Per-thread staging chunk assignments (1024 chunks of 16 B per array).
    const int q2 = tid + 512;
    const int er1 = tid >> 3, ec1 = (tid & 7) * 8;   // Ehi/Elo chunk 1
    const int er2 = q2  >> 3, ec2 = (q2  & 7) * 8;   // Ehi/Elo chunk 2
    const int tr1 = tid >> 4, tc1 = (tid & 15) * 8;  // EhiT chunk 1
    const int tr2 = q2  >> 4, tc2 = (q2  & 15) * 8;  // EhiT chunk 2

    // Persistent Ei A-frags (hi & lo), K=64 -> 2 ksteps
    const __hip_bfloat16* eih = e_hi + (size_t)(b * N_ + m0 + l16) * D_;
    const __hip_bfloat16* eil = e_lo + (size_t)(b * N_ + m0 + l16) * D_;
    bf16x8 ahi[2], alo[2];
#pragma unroll
    for (int ks = 0; ks < 2; ks++) {
        ahi[ks] = ld_frag(eih + ks * 32 + quad * 8);
        alo[ks] = ld_frag(eil + ks * 32 + quad * 8);
    }

    f32x4 o[4];
#pragma unroll
    for (int nt = 0; nt < 4; nt++) o[nt] = f32x4{0.f, 0.f, 0.f, 0.f};

    float* lp_out = out + (size_t)B_ * N_ * D_;

    // ---- preload staged panel regs for jt = 0 ----
    uint4 gh0, gh1, gl0, gl1, gt0, gt1;
    {
        gh0 = *(const uint4*)(e_hi + (size_t)(b * N_ + er1) * D_ + ec1);
        gh1 = *(const uint4*)(e_hi + (size_t)(b * N_ + er2) * D_ + ec2);
        gl0 = *(const uint4*)(e_lo + (size_t)(b * N_ + er1) * D_ + ec1);
        gl1 = *(const uint4*)(e_lo + (size_t)(b * N_ + er2) * D_ + ec2);
        gt0 = *(const uint4*)(e_hiT + (size_t)(b * D_ + tr1) * N_ + tc1);
        gt1 = *(const uint4*)(e_hiT + (size_t)(b * D_ + tr2) * N_ + tc2);
    }

    for (int jt = 0; jt < 16; jt++) {
        lds_barrier();   // Ba: jt-1's panel reads + trans writes complete

        // ---- lp(jt-1) -> global NT (512 B chunks), || with panel ds_write ----
        if (jt > 0) {
            const int jc0 = (jt - 1) * 128;
#pragma unroll
            for (int p = 0; p < 2; p++) {
                const int q = tid + p * 512;          // 0..1023
                const int r = q >> 5, c = (q & 31) * 4;
                __builtin_nontemporal_store(
                    *(const f32x4*)(sLpF + r * LDF + c),
                    (f32x4*)(lp_out + ((size_t)(b * N_ + i0 + r)) * N_ + jc0 + c));
            }
        }

        // ---- ds_write staged panel jt (counted vmcnt on reg deps) ----
        *(uint4*)(sEhi  + er1 * LDE + ec1) = gh0;
        *(uint4*)(sEhi  + er2 * LDE + ec2) = gh1;
        *(uint4*)(sElo  + er1 * LDE + ec1) = gl0;
        *(uint4*)(sElo  + er2 * LDE + ec2) = gl1;
        *(uint4*)(sEhiT + tr1 * LDT + tc1) = gt0;
        *(uint4*)(sEhiT + tr2 * LDT + tc2) = gt1;

        lds_barrier();   // Bb: panel jt visible; store-reads of jt-1 done

        // ---- issue staged loads for jt+1 (in flight through Gram/trans/PV) ----
        {
            const int j0n = ((jt + 1) & 15) * 128;    // wrap: harmless prefetch
            gh0 = *(const uint4*)(e_hi + (size_t)(b * N_ + j0n + er1) * D_ + ec1);
            gh1 = *(const uint4*)(e_hi + (size_t)(b * N_ + j0n + er2) * D_ + ec2);
            gl0 = *(const uint4*)(e_lo + (size_t)(b * N_ + j0n + er1) * D_ + ec1);
            gl1 = *(const uint4*)(e_lo + (size_t)(b * N_ + j0n + er2) * D_ + ec2);
            gt0 = *(const uint4*)(e_hiT + (size_t)(b * D_ + tr1) * N_ + j0n + tc1);
            gt1 = *(const uint4*)(e_hiT + (size_t)(b * D_ + tr2) * N_ + j0n + tc2);
        }

        // ---- Gram: S[16 x 32] per wave from LDS, split product, tanh/relu ----
#pragma unroll
        for (int ntl = 0; ntl < 2; ntl++) {
            const int n0 = h * 32 + ntl * 16;
            f32x4 s = f32x4{0.f, 0.f, 0.f, 0.f};
#pragma unroll
            for (int ks = 0; ks < 2; ks++) {
                const int ko = ks * 32 + quad * 8;
                bf16x8 bhi = ld_frag(sEhi + (n0 + l16) * LDE + ko);
                bf16x8 blo = ld_frag(sElo + (n0 + l16) * LDE + ko);
                s = __builtin_amdgcn_mfma_f32_16x16x32_bf16(ahi[ks], bhi, s, 0, 0, 0);
                s = __builtin_amdgcn_mfma_f32_16x16x32_bf16(ahi[ks], blo, s, 0, 0, 0);
                s = __builtin_amdgcn_mfma_f32_16x16x32_bf16(alo[ks], bhi, s, 0, 0, 0);
            }
#pragma unroll
            for (int i = 0; i < 4; i++) {
                // relu(tanh(t)) = tanh(max(t,0)) — clamp BEFORE exp2: no
                // overflow path, and fmaxf(NaN,0)=0 absorbs upstream garbage.
                const float tc = fmaxf(s[i], 0.0f);
                const float z = __builtin_amdgcn_exp2f(tc * -2.8853900817779268f);
                const float v = (1.0f - z) * __builtin_amdgcn_rcpf(1.0f + z);
                sLpF[(g * 16 + quad * 4 + i) * LDF + n0 + l16] = v;
            }
        }

        // ---- PV: self-read own 16x32 block (same-wave RAW) + sEhiT frags ----
        {
            bf16x8 a = cvt8(sLpF + (g * 16 + l16) * LDF + koff);
#pragma unroll
            for (int nt = 0; nt < 4; nt++) {
                bf16x8 bfr = ld_frag(sEhiT + (nt * 16 + l16) * LDT + koff);
                o[nt] = __builtin_amdgcn_mfma_f32_16x16x32_bf16(a, bfr, o[nt], 0, 0, 0);
            }
        }
    }

    // ---- drain: store lp tile 15 ----
    lds_barrier();
    {
        const int jc0 = 15 * 128;
#pragma unroll
        for (int p = 0; p < 2; p++) {
            const int q = tid + p * 512;
            const int r = q >> 5, c = (q & 31) * 4;
            __builtin_nontemporal_store(
                *(const f32x4*)(sLpF + r * LDF + c),
                (f32x4*)(lp_out + ((size_t)(b * N_ + i0 + r)) * N_ + jc0 + c));
        }
    }
    lds_barrier();   // store-reads done before sO overlay

    // ---- epilogue: sum 4 j-quarter partials, /N, store node_feats (fp32) ----
    float* sO = (float*)smem;   // overlay (34.8 KB)
#pragma unroll
    for (int nt = 0; nt < 4; nt++) {
#pragma unroll
        for (int i = 0; i < 4; i++) {
            const int row = quad * 4 + i;            // local row in group
            const int chan = nt * 16 + l16;
            sO[w * 1088 + row * 68 + chan] = o[nt][i];   // stride 68: 2-way banks
        }
    }
    lds_barrier();
    {
        const int row = tid >> 4;                    // 0..31
        const int c4  = (tid & 15) * 4;
        const int gg = row >> 4, rr = row & 15;
        const float* base = sO + (gg * 4) * 1088 + rr * 68 + c4;
        const float4 v0 = *(const float4*)(base);
        const float4 v1 = *(const float4*)(base + 1088);
        const float4 v2 = *(const float4*)(base + 2176);
        const float4 v3 = *(const float4*)(base + 3264);
        f32x4 r;
        r[0] = (v0.x + v1.x + v2.x + v3.x) * (1.0f / 2048.0f);
        r[1] = (v0.y + v1.y + v2.y + v3.y) * (1.0f / 2048.0f);
        r[2] = (v0.z + v1.z + v2.z + v3.z) * (1.0f / 2048.0f);
        r[3] = (v0.w + v1.w + v2.w + v3.w) * (1.0f / 2048.0f);
        *reinterpret_cast<f32x4*>(out + ((size_t)(b * N_ + i0 + row)) * D_ + c4) = r;
    }
}

// ---------------------------------------------------------------------------
extern "C" void kernel_launch(void* const* d_in, const int* in_sizes, int n_in,
                              void* d_out, int out_size, void* d_ws, size_t ws_size,
                              hipStream_t stream) {
    const float* x    = (const float*)d_in[0];
    const float* W    = (const float*)d_in[1];
    const float* bias = (const float*)d_in[2];
    float* out = (float*)d_out;

    __hip_bfloat16* e_hi  = (__hip_bfloat16*)d_ws;            // [B*N][64]
    __hip_bfloat16* e_lo  = e_hi + (size_t)B_ * N_ * D_;      // [B*N][64]
    __hip_bfloat16* e_hiT = e_lo + (size_t)B_ * N_ * D_;      // [B][64][N]

    ex_kernel<<<dim3(256), dim3(256), 0, stream>>>(x, W, bias, e_hi, e_lo, e_hiT);
    fused_kernel<<<dim3(8, 64), dim3(512), 0, stream>>>(e_hi, e_lo, e_hiT, out);
}